// Round 14
// baseline (78.957 us; speedup 1.0000x reference)
//
#include <hip/hip_runtime.h>
#include <hip/hip_bf16.h>

// RuleGraphConvLayer R14 = R13 minus lds_self:
// nei-only LDS (24.8 KB -> 6 blocks/CU), self rows read from global in P3
// (block-contiguous, L1/L2-hot), cs folded into P3 per-lane.
// K slots: [0..80] self, [81..95] pad(B=0), [96..176] comb, [177..191] pad.
constexpr int kNodes = 262144;
constexpr int NC  = 103;   // feature columns
constexpr int F   = 81;    // used features
constexpr int OC  = 128;   // output channels
constexpr int NKS = 6;     // 6*32 = 192 K slots
constexpr int NPB = 64;    // nodes per block
constexpr int THREADS = 256;
constexpr int NST = 96;    // nei LDS row stride (dwords), 16B-chunk XOR swizzle

typedef __attribute__((ext_vector_type(8))) short bf16x8;
typedef __attribute__((ext_vector_type(4))) float f32x4;
typedef float f32x4u __attribute__((ext_vector_type(4))) __attribute__((aligned(4)));

__device__ inline ushort f2bf(float f) {
  uint u = __float_as_uint(f);
  return (ushort)((u + 0x7fffu + ((u >> 16) & 1u)) >> 16);  // RNE
}
__device__ inline short bfc(float x) {
  return (short)__bfloat16_as_ushort(__float2bfloat16(x));
}

__device__ __forceinline__ void gll4(const float* g, float* l) {
  __builtin_amdgcn_global_load_lds(
      (const __attribute__((address_space(1))) unsigned int*)g,
      (__attribute__((address_space(3))) unsigned int*)l, 4, 0, 0);
}

// B table in fragment order: wf[ks][ct][lane] = 8 bf16.
// B[k][c]: k = ks*32 + (lane>>4)*8 + i, c = ct*16 + (lane&15).
// Rows: k<81 -> w_s[k]; 96<=k<177 -> w_n[k-96]; else 0.
__global__ __launch_bounds__(256)
void prep_w(const float* __restrict__ w_s, const float* __restrict__ w_n,
            ushort* __restrict__ wf) {
  int t = blockIdx.x * 256 + threadIdx.x;
  if (t >= NKS * 8 * 64) return;
  int l  = t & 63;
  int ct = (t >> 6) & 7;
  int ks = t >> 9;
  int c  = ct * 16 + (l & 15);
  int kb = ks * 32 + ((l >> 4) << 3);
  union { ushort u[8]; int4 v; } o;
  #pragma unroll
  for (int i = 0; i < 8; ++i) {
    int k = kb + i;
    float f = 0.f;
    if (k < F)                      f = w_s[k * OC + c];
    else if (k >= 96 && k < 96 + F) f = w_n[(k - 96) * OC + c];
    o.u[i] = f2bf(f);
  }
  ((int4*)wf)[t] = o.v;
}

__global__ __launch_bounds__(THREADS)
void rgc_v14(const float* __restrict__ feat, const ushort* __restrict__ wf,
             float* __restrict__ out) {
  __shared__ __align__(16) float lds_nei[NPB * NST];   // 24576 B (swizzled)
  __shared__ int s_sel[NPB];

  const int tid = threadIdx.x;
  const int w   = tid >> 6;
  const int l   = tid & 63;
  const long base = (long)blockIdx.x * NPB;

  // ---- Hoisted B fragments: wave w owns ct = {w, w+4} (12 x 16B, once).
  const bf16x8* wfv = (const bf16x8*)wf;
  bf16x8 bA[NKS], bB[NKS];
  #pragma unroll
  for (int ks = 0; ks < NKS; ++ks) {
    bA[ks] = wfv[(ks * 8 + w)     * 64 + l];
    bB[ks] = wfv[(ks * 8 + w + 4) * 64 + l];
  }

  // ---- P0: neighbor select only (2 dwords/node), lanes 0..15 of wave w.
  if (l < 16) {
    const int n = w * 16 + l;
    const float* row = feat + (base + n) * NC;
    float f0 = row[F], f1 = row[F + 1];
    int i0 = (int)f0, i1 = (int)f1;
    s_sel[n] = (i1 != 0) ? i1 : i0;          // alive <=> sel != 0
  }
  asm volatile("s_waitcnt lgkmcnt(0)" ::: "memory");  // s_sel visible
  __builtin_amdgcn_s_barrier();

  // ---- P1: nei gather DMA. LDS dword p of a row holds logical col
  // (c<<5) + ((x^(row&7))<<2) + cl where p = (c<<5)+(x<<2)+cl  (involution).
  #pragma unroll
  for (int j = 0; j < 24; ++j) {
    int v   = tid + j * THREADS;            // 0..6143
    int row = v / NST;
    int p   = v - row * NST;
    int c   = p >> 5;
    int x   = (p >> 2) & 7;
    int cl  = p & 3;
    int col = (c << 5) + ((x ^ (row & 7)) << 2) + cl;
    gll4(feat + (long)s_sel[row] * NC + col,
         lds_nei + (j * THREADS + w * 64));
  }
  asm volatile("s_waitcnt vmcnt(0)" ::: "memory");    // gather landed
  __builtin_amdgcn_s_barrier();

  // ---- P3: 4 node-tiles x 2 column tiles. Self from GLOBAL (L1/L2-hot),
  // nei from LDS, cs computed per-lane (redundant x16, VALU-cheap).
  const int q    = l >> 4;
  const int lrow = l & 15;
  const int off0 = q * 8;
  const int col  = l & 15;

  #pragma unroll 1
  for (int nt = 0; nt < 4; ++nt) {
    const int n = nt * 16 + lrow;
    const int r = n & 7;
    const float* srow = feat + (base + n) * NC;
    const float* np   = lds_nei + n * NST;
    const int sel     = s_sel[n];
    const float alive = (sel != 0) ? 1.f : 0.f;

    // Self chunks (2 unaligned f32x4 per group) + coords.
    f32x4u s8[3][2];
    #pragma unroll
    for (int c = 0; c < 3; ++c) {
      s8[c][0] = *(const f32x4u*)(srow + c * 32 + off0);
      s8[c][1] = *(const f32x4u*)(srow + c * 32 + off0 + 4);
    }
    float sc0 = srow[0], sc1 = srow[1], sc2 = srow[2];

    // cs = alive / d^2 from LDS nei coords (logical cols 0..2 -> chunk r).
    float nx = np[(r << 2) + 0];
    float ny = np[(r << 2) + 1];
    float nz = np[(r << 2) + 2];
    float dx = sc0 - nx, dy = sc1 - ny, dz = sc2 - nz;
    float d2 = dx * dx + dy * dy + dz * dz;
    float cs = alive * ((d2 > 0.f) ? (1.f / d2) : 10000.f);

    // A fragments; nei chunks read at swizzled offsets (b128).
    bf16x8 afS[3], afC[3];
    #pragma unroll
    for (int c = 0; c < 3; ++c) {
      f32x4 lo = *(const f32x4*)(np + c * 32 + (((2 * q)     ^ r) << 2));
      f32x4 hi = *(const f32x4*)(np + c * 32 + (((2 * q + 1) ^ r) << 2));
      #pragma unroll
      for (int i = 0; i < 8; ++i) {
        float sv = s8[c][i >> 2][i & 3];
        float nv = (i < 4) ? lo[i] : hi[i - 4];
        afS[c][i] = bfc(sv * alive);
        float se = sv;
        if (c == 0 && i < 3 && q == 0) se = 0.f;  // comb kk<3: nei coords only
        afC[c][i] = bfc((nv + se) * cs);
      }
    }

    f32x4 a0 = (f32x4)(0.f), a1 = (f32x4)(0.f);
    #pragma unroll
    for (int ks = 0; ks < NKS; ++ks) {
      bf16x8 af = (ks < 3) ? afS[ks] : afC[ks - 3];
      a0 = __builtin_amdgcn_mfma_f32_16x16x32_bf16(af, bA[ks], a0, 0, 0, 0);
      a1 = __builtin_amdgcn_mfma_f32_16x16x32_bf16(af, bB[ks], a1, 0, 0, 0);
    }

    // C/D: col = lane&15, row = (lane>>4)*4 + reg  [m89/m91]
    const long orow = base + nt * 16 + q * 4;
    #pragma unroll
    for (int rr = 0; rr < 4; ++rr) {
      out[(orow + rr) * OC + w * 16       + col] = a0[rr];
      out[(orow + rr) * OC + (w + 4) * 16 + col] = a1[rr];
    }
  }
}

extern "C" void kernel_launch(void* const* d_in, const int* in_sizes, int n_in,
                              void* d_out, int out_size, void* d_ws, size_t ws_size,
                              hipStream_t stream) {
  const float* feat = (const float*)d_in[0];
  const float* w_s  = (const float*)d_in[1];
  const float* w_n  = (const float*)d_in[2];
  float* outp = (float*)d_out;
  ushort* wf = (ushort*)d_ws;  // 6*8*64*8 bf16 = 49152 bytes

  prep_w<<<dim3((NKS * 8 * 64 + 255) / 256), 256, 0, stream>>>(w_s, w_n, wf);
  rgc_v14<<<dim3(kNodes / NPB), THREADS, 0, stream>>>(feat, wf, outp);
}

// Round 15
// 76.322 us; speedup vs baseline: 1.0345x; 1.0345x over previous
//
#include <hip/hip_runtime.h>
#include <hip/hip_bf16.h>

// RuleGraphConvLayer R15 = R13 compute + T3/T4 intra-block pipeline:
// block = 256 nodes = 8 tiles x 32; self+nei DMA-staged (gll4, uniform
// 25 VMEM/thread/tile) into double-buffered LDS; raw s_barrier + counted
// vmcnt (never 0 in steady state) so gather(t+1) flies under MFMA(t).
// K slots: [0..80] self, [81..95] pad(B=0), [96..176] comb, [177..191] pad.
constexpr int kNodes = 262144;
constexpr int NC  = 103;   // feature columns
constexpr int F   = 81;    // used features
constexpr int OC  = 128;   // output channels
constexpr int NKS = 6;     // 6*32 = 192 K slots
constexpr int TN  = 32;    // nodes per tile
constexpr int TPB = 8;     // tiles per block -> 256 nodes
constexpr int THREADS = 256;
constexpr int SELF_DW = 3328;  // 13*256 staged dwords (3296 used, stride 103)
constexpr int NEI_DW  = 3072;  // 32 rows x 96 dwords (chunk-XOR swizzled)

typedef __attribute__((ext_vector_type(8))) short bf16x8;
typedef __attribute__((ext_vector_type(4))) float f32x4;

__device__ inline ushort f2bf(float f) {
  uint u = __float_as_uint(f);
  return (ushort)((u + 0x7fffu + ((u >> 16) & 1u)) >> 16);  // RNE
}
__device__ inline short bfc(float x) {
  return (short)__bfloat16_as_ushort(__float2bfloat16(x));
}
__device__ __forceinline__ void gll4(const float* g, const float* l) {
  __builtin_amdgcn_global_load_lds(
      (const __attribute__((address_space(1))) unsigned int*)g,
      (__attribute__((address_space(3))) unsigned int*)l, 4, 0, 0);
}

// B table in fragment order: wf[ks][ct][lane] = 8 bf16.
// B[k][c]: k = ks*32 + (lane>>4)*8 + i, c = ct*16 + (lane&15).
// Rows: k<81 -> w_s[k]; 96<=k<177 -> w_n[k-96]; else 0.
__global__ __launch_bounds__(256)
void prep_w(const float* __restrict__ w_s, const float* __restrict__ w_n,
            ushort* __restrict__ wf) {
  int t = blockIdx.x * 256 + threadIdx.x;
  if (t >= NKS * 8 * 64) return;
  int l  = t & 63;
  int ct = (t >> 6) & 7;
  int ks = t >> 9;
  int c  = ct * 16 + (l & 15);
  int kb = ks * 32 + ((l >> 4) << 3);
  union { ushort u[8]; int4 v; } o;
  #pragma unroll
  for (int i = 0; i < 8; ++i) {
    int k = kb + i;
    float f = 0.f;
    if (k < F)                      f = w_s[k * OC + c];
    else if (k >= 96 && k < 96 + F) f = w_n[(k - 96) * OC + c];
    o.u[i] = f2bf(f);
  }
  ((int4*)wf)[t] = o.v;
}

__global__ __launch_bounds__(THREADS)
void rgc_v15(const float* __restrict__ feat, const ushort* __restrict__ wf,
             float* __restrict__ out) {
  __shared__ __align__(16) float sA[2][SELF_DW];  // 26624 B
  __shared__ __align__(16) float sN[2][NEI_DW];   // 24576 B
  __shared__ int s_sel[THREADS];                  // 256 nodes

  const int tid = threadIdx.x;
  const int w   = tid >> 6;
  const int l   = tid & 63;
  const long gbase = (long)blockIdx.x * (TN * TPB);
  const long MAXO  = (long)kNodes * NC - 1;

  // ---- Hoisted B fragments: wave w owns ct = {w, w+4} (12 x 16B, once).
  const bf16x8* wfv = (const bf16x8*)wf;
  bf16x8 bA[NKS], bB[NKS];
  #pragma unroll
  for (int ks = 0; ks < NKS; ++ks) {
    bA[ks] = wfv[(ks * 8 + w)     * 64 + l];
    bB[ks] = wfv[(ks * 8 + w + 4) * 64 + l];
  }

  // ---- P0: sel for all 256 nodes (one per thread, single exposure).
  {
    const float* row = feat + (gbase + tid) * NC;
    float f0 = row[F], f1 = row[F + 1];
    int i0 = (int)f0, i1 = (int)f1;
    s_sel[tid] = (i1 != 0) ? i1 : i0;     // alive <=> sel != 0
  }
  asm volatile("s_waitcnt lgkmcnt(0)" ::: "memory");
  asm volatile("s_barrier" ::: "memory");

  // ---- STAGE(T -> buffer B): 25 uniform gll4 per thread.
#define STAGE(T, B)                                                          \
  {                                                                          \
    const long tb = (gbase + (long)(T) * TN) * NC;                           \
    _Pragma("unroll")                                                        \
    for (int j = 0; j < 13; ++j) {       /* self: contiguous, clamped */     \
      long off = tb + (j * THREADS + tid);                                   \
      off = (off < MAXO) ? off : MAXO;                                       \
      gll4(feat + off, &sA[B][j * THREADS + w * 64]);                        \
    }                                                                        \
    _Pragma("unroll")                                                        \
    for (int j = 0; j < 12; ++j) {       /* nei: chunk-XOR swizzled src */   \
      int v  = tid + j * THREADS;        /* 0..3071 */                       \
      int r  = v / 96;                                                       \
      int p  = v - r * 96;                                                   \
      int c  = p >> 5, x = (p >> 2) & 7, cl = p & 3;                         \
      int col = (c << 5) + ((x ^ (r & 7)) << 2) + cl;                        \
      gll4(feat + (long)s_sel[(T) * TN + r] * NC + col,                      \
           &sN[B][j * THREADS + w * 64]);                                    \
    }                                                                        \
  }

  STAGE(0, 0);
  STAGE(1, 1);

  const int q    = l >> 4;
  const int lrow = l & 15;
  const int off0 = q * 8;
  const int col  = l & 15;

  #pragma unroll 1
  for (int t = 0; t < TPB; ++t) {
    // Counted waits: stage(t) landed; stage(t+1)+stores may stay in flight.
    if (t == 0)            asm volatile("s_waitcnt vmcnt(25)" ::: "memory");
    else if (t == TPB - 1) asm volatile("s_waitcnt vmcnt(16)" ::: "memory");
    else                   asm volatile("s_waitcnt vmcnt(41)" ::: "memory");
    asm volatile("s_barrier" ::: "memory");   // all waves' stage(t) landed

    const float* selfb = &sA[t & 1][0];
    const float* neib  = &sN[t & 1][0];

    #pragma unroll
    for (int nt = 0; nt < 2; ++nt) {
      const int tn = nt * 16 + lrow;
      const int r  = tn & 7;
      const float* sp = selfb + tn * NC;     // stride 103 (scalar reads)
      const float* np = neib + tn * 96;      // swizzled chunks (b128 reads)
      const int sel   = s_sel[t * TN + tn];
      const float alive = (sel != 0) ? 1.f : 0.f;

      // cs = alive / d^2 (nei coords at swizzled chunk r).
      float dx = sp[0] - np[(r << 2) + 0];
      float dy = sp[1] - np[(r << 2) + 1];
      float dz = sp[2] - np[(r << 2) + 2];
      float d2 = dx * dx + dy * dy + dz * dz;
      float cs = alive * ((d2 > 0.f) ? (1.f / d2) : 10000.f);

      bf16x8 afS[3], afC[3];
      #pragma unroll
      for (int c = 0; c < 3; ++c) {
        f32x4 lo = *(const f32x4*)(np + c * 32 + (((2 * q)     ^ r) << 2));
        f32x4 hi = *(const f32x4*)(np + c * 32 + (((2 * q + 1) ^ r) << 2));
        #pragma unroll
        for (int i = 0; i < 8; ++i) {
          float sv = sp[c * 32 + off0 + i];
          float nv = (i < 4) ? lo[i] : hi[i - 4];
          afS[c][i] = bfc(sv * alive);
          float se = sv;
          if (c == 0 && i < 3 && q == 0) se = 0.f;  // comb kk<3: nei only
          afC[c][i] = bfc((nv + se) * cs);
        }
      }

      f32x4 a0 = (f32x4)(0.f), a1 = (f32x4)(0.f);
      #pragma unroll
      for (int ks = 0; ks < NKS; ++ks) {
        bf16x8 af = (ks < 3) ? afS[ks] : afC[ks - 3];
        a0 = __builtin_amdgcn_mfma_f32_16x16x32_bf16(af, bA[ks], a0, 0, 0, 0);
        a1 = __builtin_amdgcn_mfma_f32_16x16x32_bf16(af, bB[ks], a1, 0, 0, 0);
      }

      // C/D: col = lane&15, row = (lane>>4)*4 + reg  [m89/m91]
      const long orow = gbase + t * TN + nt * 16 + q * 4;
      #pragma unroll
      for (int rr = 0; rr < 4; ++rr) {    // 16 stores/thread/tile (counted)
        out[(orow + rr) * OC + w * 16       + col] = a0[rr];
        out[(orow + rr) * OC + (w + 4) * 16 + col] = a1[rr];
      }
    }

    asm volatile("s_barrier" ::: "memory");   // all waves done reading buf
    if (t + 2 < TPB) STAGE(t + 2, t & 1);     // refill the buffer just freed
  }
#undef STAGE
}

extern "C" void kernel_launch(void* const* d_in, const int* in_sizes, int n_in,
                              void* d_out, int out_size, void* d_ws, size_t ws_size,
                              hipStream_t stream) {
  const float* feat = (const float*)d_in[0];
  const float* w_s  = (const float*)d_in[1];
  const float* w_n  = (const float*)d_in[2];
  float* outp = (float*)d_out;
  ushort* wf = (ushort*)d_ws;  // 6*8*64*8 bf16 = 49152 bytes

  prep_w<<<dim3((NKS * 8 * 64 + 255) / 256), 256, 0, stream>>>(w_s, w_n, wf);
  rgc_v15<<<dim3(kNodes / (TN * TPB)), THREADS, 0, stream>>>(feat, wf, outp);
}

// Round 16
// 67.559 us; speedup vs baseline: 1.1687x; 1.1297x over previous
//
#include <hip/hip_runtime.h>
#include <hip/hip_bf16.h>

// RuleGraphConvLayer R16 = R13 (champion) minus the P2 phase:
// cs = alive/d^2 computed per-lane in P3 from LDS (bit-identical math),
// removing one barrier + one serialized 64-thread phase.
// Staging: self via gll16 DMA (linear), nei via gll4 DMA with 16B-chunk
// XOR-swizzled source (involution); compute reads swizzled b128.
// K slots: [0..80] self, [81..95] pad(B=0), [96..176] comb, [177..191] pad.
constexpr int kNodes = 262144;
constexpr int NC  = 103;   // feature columns
constexpr int F   = 81;    // used features
constexpr int OC  = 128;   // output channels
constexpr int NKS = 6;     // 6*32 = 192 K slots
constexpr int NPB = 64;    // nodes per block
constexpr int THREADS = 256;
constexpr int NST = 96;    // nei LDS row stride (dwords)
constexpr int SELF_F4 = NPB * NC / 4;  // 1648

typedef __attribute__((ext_vector_type(8))) short bf16x8;
typedef __attribute__((ext_vector_type(4))) float f32x4;

__device__ inline ushort f2bf(float f) {
  uint u = __float_as_uint(f);
  return (ushort)((u + 0x7fffu + ((u >> 16) & 1u)) >> 16);  // RNE
}
__device__ inline short bfc(float x) {
  return (short)__bfloat16_as_ushort(__float2bfloat16(x));
}

__device__ __forceinline__ void gll4(const float* g, float* l) {
  __builtin_amdgcn_global_load_lds(
      (const __attribute__((address_space(1))) unsigned int*)g,
      (__attribute__((address_space(3))) unsigned int*)l, 4, 0, 0);
}
__device__ __forceinline__ void gll16(const float* g, float* l) {
  __builtin_amdgcn_global_load_lds(
      (const __attribute__((address_space(1))) unsigned int*)g,
      (__attribute__((address_space(3))) unsigned int*)l, 16, 0, 0);
}

// B table in fragment order: wf[ks][ct][lane] = 8 bf16.
// B[k][c]: k = ks*32 + (lane>>4)*8 + i, c = ct*16 + (lane&15).
// Rows: k<81 -> w_s[k]; 96<=k<177 -> w_n[k-96]; else 0.
__global__ __launch_bounds__(256)
void prep_w(const float* __restrict__ w_s, const float* __restrict__ w_n,
            ushort* __restrict__ wf) {
  int t = blockIdx.x * 256 + threadIdx.x;
  if (t >= NKS * 8 * 64) return;
  int l  = t & 63;
  int ct = (t >> 6) & 7;
  int ks = t >> 9;
  int c  = ct * 16 + (l & 15);
  int kb = ks * 32 + ((l >> 4) << 3);
  union { ushort u[8]; int4 v; } o;
  #pragma unroll
  for (int i = 0; i < 8; ++i) {
    int k = kb + i;
    float f = 0.f;
    if (k < F)                      f = w_s[k * OC + c];
    else if (k >= 96 && k < 96 + F) f = w_n[(k - 96) * OC + c];
    o.u[i] = f2bf(f);
  }
  ((int4*)wf)[t] = o.v;
}

__global__ __launch_bounds__(THREADS)
void rgc_v16(const float* __restrict__ feat, const ushort* __restrict__ wf,
             float* __restrict__ out) {
  __shared__ __align__(16) float lds_self[NPB * NC];   // 26368 B (stride 103)
  __shared__ __align__(16) float lds_nei[NPB * NST];   // 24576 B (stride 96, swz)
  __shared__ int s_sel[NPB];

  const int tid = threadIdx.x;
  const int w   = tid >> 6;
  const int l   = tid & 63;
  const long base = (long)blockIdx.x * NPB;
  const float* fbase = feat + base * NC;

  // ---- Hoisted B fragments: wave w owns ct = {w, w+4} (12 x 16B, once).
  const bf16x8* wfv = (const bf16x8*)wf;
  bf16x8 bA[NKS], bB[NKS];
  #pragma unroll
  for (int ks = 0; ks < NKS; ++ks) {
    bA[ks] = wfv[(ks * 8 + w)     * 64 + l];
    bB[ks] = wfv[(ks * 8 + w + 4) * 64 + l];
  }

  // ---- P0: fire self-copy DMA (stays in flight across the barrier),
  // and resolve sel per node (lanes 0..15 of wave w -> nodes w*16+l).
  #pragma unroll
  for (int j = 0; j < 7; ++j) {
    int i = tid + j * THREADS;              // f4 index
    if (j < 6 || i < SELF_F4) {
      gll16((const float*)((const float4*)fbase + i),
            (float*)((float4*)lds_self + (j * THREADS + w * 64)));
    }
  }
  if (l < 16) {
    const int n = w * 16 + l;
    const float* row = feat + (base + n) * NC;
    float f0 = row[F], f1 = row[F + 1];
    int i0 = (int)f0, i1 = (int)f1;
    s_sel[n] = (i1 != 0) ? i1 : i0;         // alive <=> sel != 0
  }
  asm volatile("s_waitcnt lgkmcnt(0)" ::: "memory");  // sel visible, DMA flying
  __builtin_amdgcn_s_barrier();

  // ---- P1: nei gather DMA. LDS dword p of a row holds logical col
  // (c<<5) + ((x^(row&7))<<2) + cl where p = (c<<5)+(x<<2)+cl (involution).
  #pragma unroll
  for (int j = 0; j < 24; ++j) {
    int v   = tid + j * THREADS;            // 0..6143
    int row = v / NST;
    int p   = v - row * NST;
    int c   = p >> 5;
    int x   = (p >> 2) & 7;
    int cl  = p & 3;
    int col = (c << 5) + ((x ^ (row & 7)) << 2) + cl;
    gll4(feat + (long)s_sel[row] * NC + col,
         lds_nei + (j * THREADS + w * 64));
  }
  asm volatile("s_waitcnt vmcnt(0) lgkmcnt(0)" ::: "memory");  // all data landed
  __builtin_amdgcn_s_barrier();

  // ---- P3: per wave, 4 node-tiles x 2 column tiles. A from LDS, B from
  // VGPRs; cs = alive/d^2 per-lane (redundant x4, bit-identical to R13).
  const int q    = l >> 4;
  const int lrow = l & 15;
  const int off0 = q * 8;
  const int col  = l & 15;

  #pragma unroll
  for (int nt = 0; nt < 4; ++nt) {
    const int n = nt * 16 + lrow;
    const int r = n & 7;
    const float* sp = lds_self + n * NC;
    const float* np = lds_nei + n * NST;
    const int sel   = s_sel[n];
    const float alive = (sel != 0) ? 1.f : 0.f;

    // nei coords: logical chunk 0 lives at physical chunk (0 ^ r) = r.
    float nx = np[(r << 2) + 0];
    float ny = np[(r << 2) + 1];
    float nz = np[(r << 2) + 2];
    float dx = sp[0] - nx, dy = sp[1] - ny, dz = sp[2] - nz;
    float d2 = dx * dx + dy * dy + dz * dz;
    float cs = alive * ((d2 > 0.f) ? (1.f / d2) : 10000.f);

    bf16x8 afS[3], afC[3];
    #pragma unroll
    for (int c = 0; c < 3; ++c) {
      // logical dwords c*32 + q*8 .. +7 = swizzled chunks (2q)^r, (2q+1)^r
      f32x4 lo = *(const f32x4*)(np + c * 32 + (((2 * q)     ^ r) << 2));
      f32x4 hi = *(const f32x4*)(np + c * 32 + (((2 * q + 1) ^ r) << 2));
      #pragma unroll
      for (int i = 0; i < 8; ++i) {
        float sv = sp[c * 32 + off0 + i];
        float nv = (i < 4) ? lo[i] : hi[i - 4];
        afS[c][i] = bfc(sv * alive);
        float se = sv;
        if (c == 0 && i < 3 && q == 0) se = 0.f;  // comb kk<3: nei coords only
        afC[c][i] = bfc((nv + se) * cs);
      }
    }

    f32x4 a0 = (f32x4)(0.f), a1 = (f32x4)(0.f);
    #pragma unroll
    for (int ks = 0; ks < NKS; ++ks) {
      bf16x8 af = (ks < 3) ? afS[ks] : afC[ks - 3];
      a0 = __builtin_amdgcn_mfma_f32_16x16x32_bf16(af, bA[ks], a0, 0, 0, 0);
      a1 = __builtin_amdgcn_mfma_f32_16x16x32_bf16(af, bB[ks], a1, 0, 0, 0);
    }

    // C/D: col = lane&15, row = (lane>>4)*4 + reg  [m89/m91]
    const long orow = base + nt * 16 + q * 4;
    #pragma unroll
    for (int rr = 0; rr < 4; ++rr) {
      out[(orow + rr) * OC + w * 16       + col] = a0[rr];
      out[(orow + rr) * OC + (w + 4) * 16 + col] = a1[rr];
    }
  }
}

extern "C" void kernel_launch(void* const* d_in, const int* in_sizes, int n_in,
                              void* d_out, int out_size, void* d_ws, size_t ws_size,
                              hipStream_t stream) {
  const float* feat = (const float*)d_in[0];
  const float* w_s  = (const float*)d_in[1];
  const float* w_n  = (const float*)d_in[2];
  float* outp = (float*)d_out;
  ushort* wf = (ushort*)d_ws;  // 6*8*64*8 bf16 = 49152 bytes

  prep_w<<<dim3((NKS * 8 * 64 + 255) / 256), 256, 0, stream>>>(w_s, w_n, wf);
  rgc_v16<<<dim3(kNodes / NPB), THREADS, 0, stream>>>(feat, wf, outp);
}